// Round 11
// baseline (320.032 us; speedup 1.0000x reference)
//
#include <hip/hip_runtime.h>
#include <hip/hip_bf16.h>
#include <math.h>

#define Bz 16
#define Nz 1024
#define Mz 4
#define Dz 128
#define Hz 4
#define VOCABz 32000
#define CAP 128
#define BNc (Bz * Nz)
#define NC 576            // 512 Wh cols (e*4+h) + 8 f-cols + 56 pad

typedef __attribute__((ext_vector_type(8))) short s16x8;
typedef __attribute__((ext_vector_type(8))) _Float16 f16x8;
typedef __attribute__((ext_vector_type(4))) float f32x4;
typedef __attribute__((ext_vector_type(2))) _Float16 f16x2;

#if defined(__has_builtin)
#if __has_builtin(__builtin_amdgcn_fdot2)
#define FDOT2(w, s, acc) acc = __builtin_amdgcn_fdot2((w), (s), (acc), false)
#endif
#endif
#ifndef FDOT2
#define FDOT2(w, s, acc) acc += (float)(w)[0] * (float)(s)[0] + (float)(w)[1] * (float)(s)[1]
#endif
#define BC16(x) __builtin_bit_cast(f16x2, (x))

__device__ inline unsigned short f32_to_f16_bits(float x) {
    _Float16 hv = (_Float16)x;
    return __builtin_bit_cast(unsigned short, hv);
}
__device__ inline unsigned pack_f16(float a, float b) {
    f16x2 p;
    p[0] = (_Float16)a;
    p[1] = (_Float16)b;
    return __builtin_bit_cast(unsigned, p);
}

// ---------------- prep: CSR (blocks <BNc) + Wcat f16 (1152 blocks) + uinit ----------------
// Wcat[hop][c][d]: c<512 -> W[hop][h=c&3][d][e=c>>2]; c in [512,520): q=c-512,
//   col = sum_e W[hop][h=q&3][d][e] * a[hop][h][(q>>2)*128+e]; c>=520 -> 0.
__global__ __launch_bounds__(256) void k_prep(const float* __restrict__ adj,
                                              const int* __restrict__ kb_len,
                                              const int* __restrict__ conv_len,
                                              const float* __restrict__ gat_W,
                                              const float* __restrict__ gat_a,
                                              const float* __restrict__ hidden,
                                              int* __restrict__ idx, int* __restrict__ cnt,
                                              unsigned short* __restrict__ wt,
                                              float* __restrict__ u) {
    int blk = blockIdx.x;
    int t = threadIdx.x;
    if (blk < BNc) {                      // CSR row
        int row = blk;
        int b = row >> 10, n = row & 1023;
        __shared__ int scnt;
        if (t == 0) scnt = 0;
        __syncthreads();
        int ctx = kb_len[b] + conv_len[b];
        const float4 av = *((const float4*)(adj + (size_t)row * Nz) + t);
        int m0 = t * 4;
#pragma unroll
        for (int k = 0; k < 4; k++) {
            float a = k == 0 ? av.x : k == 1 ? av.y : k == 2 ? av.z : av.w;
            int m = m0 + k;
            bool on = (a > 0.f) || (m == n && n >= ctx);
            if (on) {
                int p = atomicAdd(&scnt, 1);
                if (p < CAP) idx[(size_t)row * CAP + p] = m;
            }
        }
        __syncthreads();
        if (t == 0) cnt[row] = scnt < CAP ? scnt : CAP;
    } else if (blk < BNc + 1152) {        // Wcat: 4*576*128 elems
        int i = (blk - BNc) * 256 + t;
        int d = i & 127;
        int rest = i >> 7;                // hop*576 + c
        int c = rest % NC;
        int hop = rest / NC;
        float v;
        if (c < 512) {
            int h = c & 3, e = c >> 2;
            v = gat_W[(((size_t)(hop * 4 + h)) * 128 + d) * 128 + e];
        } else if (c < 520) {
            int q = c - 512;
            int h = q & 3, which = q >> 2;
            const float* wrow = gat_W + (((size_t)(hop * 4 + h)) * 128 + d) * 128;
            const float* arow = gat_a + ((size_t)(hop * 4 + h)) * 256 + which * 128;
            float s = 0.f;
            for (int e = 0; e < 128; e++) s += wrow[e] * arow[e];
            v = s;
        } else {
            v = 0.f;
        }
        wt[i] = f32_to_f16_bits(v);
    } else {                              // u init
        int i = (blk - BNc - 1152) * 256 + t;
        if (i < Bz * Dz) u[i] = hidden[i];
    }
}

// ---------------- embed all 4 hops: x = sum emb rows (+ dh), store f16 --------------------
__global__ __launch_bounds__(128) void k_embed4(const int* __restrict__ story,
                                                const float* __restrict__ emb,
                                                const float* __restrict__ dh,
                                                const int* __restrict__ kb_len,
                                                const int* __restrict__ conv_len,
                                                unsigned short* __restrict__ xhi) {
    int row = blockIdx.x;                 // b*N + n
    int b = row >> 10, n = row & 1023;
    int d = threadIdx.x;                  // 128
    const int* st = story + (size_t)row * Mz;
    int s0 = st[0], s1 = st[1], s2 = st[2], s3 = st[3];
    int rel = n - (kb_len[b] - 1);
    float dhv = (rel >= 0 && rel < conv_len[b]) ? dh[((size_t)(b << 10) + rel) * Dz + d] : 0.f;
#pragma unroll
    for (int hop = 0; hop < 4; hop++) {
        const float* ek = emb + (size_t)hop * VOCABz * Dz;
        float acc = ek[(size_t)s0 * Dz + d] + ek[(size_t)s1 * Dz + d]
                  + ek[(size_t)s2 * Dz + d] + ek[(size_t)s3 * Dz + d] + dhv;
        xhi[(size_t)hop * BNc * Dz + (size_t)row * Dz + d] = f32_to_f16_bits(acc);
    }
}

// ---------------- GEMM X@Wcat (f16 MFMA): WhT f16 [hop][row][c], ff fp32 [hop][row][8] ----
#define AST 72
__global__ __launch_bounds__(256) void k_whf4(const unsigned short* __restrict__ xhi_a,
                                              const unsigned short* __restrict__ wt_a,
                                              unsigned short* __restrict__ WhT_a,
                                              float* __restrict__ ff) {
    int blk = blockIdx.x;
    int xcd = blk & 7;
    int s = blk >> 3;
    int hop = s / 144;
    int r = s - hop * 144;
    int rt = r / 9;
    int ct = r - rt * 9;
    int row0 = (xcd * 16 + rt) * 128;
    int t = threadIdx.x;
    int wave = t >> 6, lane = t & 63;
    int quad = lane >> 4, l16 = lane & 15;

    const unsigned short* xhi = xhi_a + (size_t)hop * BNc * Dz;
    const unsigned short* wt = wt_a + (size_t)hop * NC * 128;

    __shared__ unsigned short Ah[128 * AST];   // X tile [r][k]
    __shared__ unsigned short Bh[64 * AST];    // Wcat tile [c][d]

    f32x4 acc[2][4];
#pragma unroll
    for (int mt = 0; mt < 2; mt++)
#pragma unroll
        for (int nt = 0; nt < 4; nt++) acc[mt][nt] = (f32x4)0.f;

    for (int ph = 0; ph < 2; ph++) {
        int kb = ph * 64;
        for (int i = t; i < 1024; i += 256) {
            int rr = i >> 3, c = (i & 7) * 8;
            *(uint4*)&Ah[rr * AST + c] = *(const uint4*)&xhi[(size_t)(row0 + rr) * Dz + kb + c];
        }
        for (int i = t; i < 512; i += 256) {
            int cr = i >> 3, cc = (i & 7) * 8;
            *(uint4*)&Bh[cr * AST + cc] =
                *(const uint4*)&wt[((size_t)(ct * 64 + cr)) * 128 + kb + cc];
        }
        __syncthreads();
#pragma unroll
        for (int ks = 0; ks < 2; ks++) {
            int ko = ks * 32 + quad * 8;
            f16x8 ah[2];
#pragma unroll
            for (int mt = 0; mt < 2; mt++) {
                int rr = wave * 32 + mt * 16 + l16;
                ah[mt] = __builtin_bit_cast(f16x8, *(const s16x8*)&Ah[rr * AST + ko]);
            }
#pragma unroll
            for (int nt = 0; nt < 4; nt++) {
                int cc = nt * 16 + l16;
                f16x8 bh = __builtin_bit_cast(f16x8, *(const s16x8*)&Bh[cc * AST + ko]);
#pragma unroll
                for (int mt = 0; mt < 2; mt++)
                    acc[mt][nt] = __builtin_amdgcn_mfma_f32_16x16x32_f16(ah[mt], bh, acc[mt][nt], 0, 0, 0);
            }
        }
        __syncthreads();
    }

    if (ct < 8) {
        // repack 128x64 f16 tile through LDS (alias Ah), then coalesced uint4 stores
        unsigned short* St = Ah;
#pragma unroll
        for (int mt = 0; mt < 2; mt++)
#pragma unroll
            for (int nt = 0; nt < 4; nt++)
#pragma unroll
                for (int reg = 0; reg < 4; reg++) {
                    int rr = wave * 32 + mt * 16 + quad * 4 + reg;
                    int cc = nt * 16 + l16;
                    St[rr * AST + cc] = f32_to_f16_bits(acc[mt][nt][reg]);
                }
        __syncthreads();
        int rr = t >> 1, seg = t & 1;
        size_t gbase = ((size_t)hop * BNc + row0 + rr) * 512 + ct * 64 + seg * 32;
#pragma unroll
        for (int k = 0; k < 4; k++) {
            uint4 vv = *(uint4*)&St[rr * AST + seg * 32 + k * 8];
            *(uint4*)&WhT_a[gbase + k * 8] = vv;
        }
    } else {
        if (l16 < 8) {
#pragma unroll
            for (int mt = 0; mt < 2; mt++)
#pragma unroll
                for (int reg = 0; reg < 4; reg++) {
                    int row = row0 + wave * 32 + mt * 16 + quad * 4 + reg;
                    ff[((size_t)hop * BNc + row) * 8 + l16] = acc[mt][0][reg];
                }
        }
    }
}

// ---------------- full-wave single-row attention (fallback: deg>32 or deg==0) -------------
__device__ void attn_row_full(const unsigned short* __restrict__ WhTb,
                              const float* __restrict__ ffh,
                              const int* __restrict__ idx, int deg, int b, int row,
                              int lane, float* __restrict__ Gp) {
    const char* wblc = (const char*)WhTb + lane * 16;
    float accx = 0.f, accy = 0.f;
    if (deg > 0) {
        int m0 = lane < deg ? idx[(size_t)row * CAP + lane] : -1;
        int m1 = lane + 64 < deg ? idx[(size_t)row * CAP + lane + 64] : -1;
        float4 f1r = *(const float4*)&ffh[(size_t)row * 8];
        int m0c = m0 < 0 ? 0 : m0, m1c = m1 < 0 ? 0 : m1;
        float4 f2a = *(const float4*)&ffh[((size_t)(b << 10) + m0c) * 8 + 4];
        float4 f2b = *(const float4*)&ffh[((size_t)(b << 10) + m1c) * 8 + 4];
        float e0[4], e1[4];
        e0[0] = f1r.x + f2a.x; e0[1] = f1r.y + f2a.y; e0[2] = f1r.z + f2a.z; e0[3] = f1r.w + f2a.w;
        e1[0] = f1r.x + f2b.x; e1[1] = f1r.y + f2b.y; e1[2] = f1r.z + f2b.z; e1[3] = f1r.w + f2b.w;
#pragma unroll
        for (int h = 0; h < 4; h++) {
            e0[h] = e0[h] >= 0.f ? e0[h] : 0.2f * e0[h];
            e1[h] = e1[h] >= 0.f ? e1[h] : 0.2f * e1[h];
            if (m0 < 0) e0[h] = -1e30f;
            if (m1 < 0) e1[h] = -1e30f;
        }
        float w0[4], w1[4];
#pragma unroll
        for (int h = 0; h < 4; h++) {
            float m = fmaxf(e0[h], e1[h]);
#pragma unroll
            for (int mm = 1; mm < 64; mm <<= 1) m = fmaxf(m, __shfl_xor(m, mm));
            w0[h] = expf(e0[h] - m);
            w1[h] = expf(e1[h] - m);
            float sm = w0[h] + w1[h];
#pragma unroll
            for (int mm = 1; mm < 64; mm <<= 1) sm += __shfl_xor(sm, mm);
            float inv = 0.25f / sm;
            w0[h] *= inv;
            w1[h] *= inv;
        }
        unsigned w01_0 = pack_f16(w0[0], w0[1]), w23_0 = pack_f16(w0[2], w0[3]);
        unsigned w01_1 = pack_f16(w1[0], w1[1]), w23_1 = pack_f16(w1[2], w1[3]);
        int moff0 = m0c << 10;
        int moff1 = m1c << 10;
        int dlo = deg < 64 ? deg : 64;
#pragma unroll 2
        for (int j = 0; j < dlo; j++) {
            int so = __builtin_amdgcn_readlane(moff0, j);
            unsigned a01 = (unsigned)__builtin_amdgcn_readlane((int)w01_0, j);
            unsigned a23 = (unsigned)__builtin_amdgcn_readlane((int)w23_0, j);
            uint4 raw = *(const uint4*)(wblc + so);
            f16x2 p01 = BC16(a01), p23 = BC16(a23);
            FDOT2(BC16(raw.x), p01, accx);
            FDOT2(BC16(raw.y), p23, accx);
            FDOT2(BC16(raw.z), p01, accy);
            FDOT2(BC16(raw.w), p23, accy);
        }
        for (int j = 0; j < deg - 64; j++) {
            int so = __builtin_amdgcn_readlane(moff1, j);
            unsigned a01 = (unsigned)__builtin_amdgcn_readlane((int)w01_1, j);
            unsigned a23 = (unsigned)__builtin_amdgcn_readlane((int)w23_1, j);
            uint4 raw = *(const uint4*)(wblc + so);
            f16x2 p01 = BC16(a01), p23 = BC16(a23);
            FDOT2(BC16(raw.x), p01, accx);
            FDOT2(BC16(raw.y), p23, accx);
            FDOT2(BC16(raw.z), p01, accy);
            FDOT2(BC16(raw.w), p23, accy);
        }
    } else {
        // all-masked row: softmax of constant -9e15 = uniform 1/N over ALL m (JAX semantics)
        for (int m = 0; m < Nz; m++) {
            uint4 raw = *(const uint4*)(wblc + (m << 10));
            accx += (float)BC16(raw.x)[0] + (float)BC16(raw.x)[1]
                  + (float)BC16(raw.y)[0] + (float)BC16(raw.y)[1];
            accy += (float)BC16(raw.z)[0] + (float)BC16(raw.z)[1]
                  + (float)BC16(raw.w)[0] + (float)BC16(raw.w)[1];
        }
        accx *= 1.f / (Hz * Nz);
        accy *= 1.f / (Hz * Nz);
    }
    *(float2*)&Gp[lane * 2] = make_float2(accx, accy);
}

// ---------------- sparse GAT attention: TWO rows per wave, manual depth-3 pipeline --------
// Fast path (both degs in [1,32]): explicit 3-stage software pipeline with named stage
// registers (forces overlapped loads the compiler refused at VGPR=24). Padding iterations
// are safe: invalid slots carry w==0 and vo->row 0 (valid memory, contributes 0).
__global__ __launch_bounds__(256) void k_attn4(const unsigned short* __restrict__ WhT_a,
                                               const float* __restrict__ ff,
                                               const int* __restrict__ idx,
                                               const int* __restrict__ cnt,
                                               float* __restrict__ G_a) {
    int blk = blockIdx.x;                 // 8192 blocks
    int xcd = blk & 7;
    int s = blk >> 3;                     // 0..1023
    int g = s >> 7;                       // 0..7
    int p = (g << 3) | xcd;               // pair 0..63
    int hop = p >> 4, b = p & 15;
    int wid = threadIdx.x >> 6, lane = threadIdx.x & 63;
    int r2 = ((s & 127) << 2) | wid;      // row-pair 0..511
    int half = lane >> 5, l32 = lane & 31;
    int n = (r2 << 1) | half;
    int row = (b << 10) | n;
    const unsigned short* WhTb = WhT_a + ((size_t)hop * BNc + ((size_t)b << 10)) * 512;
    const float* ffh = ff + (size_t)hop * BNc * 8;
    int deg = cnt[row];
    int deg0 = __shfl(deg, 0), deg1 = __shfl(deg, 32);
    if (deg0 > 0 && deg1 > 0 && deg0 <= 32 && deg1 <= 32) {
        int m = l32 < deg ? idx[(size_t)row * CAP + l32] : -1;
        int mc = m < 0 ? 0 : m;
        float4 f1r = *(const float4*)&ffh[(size_t)row * 8];
        float4 f2m = *(const float4*)&ffh[((size_t)(b << 10) + mc) * 8 + 4];
        float e[4];
        e[0] = f1r.x + f2m.x; e[1] = f1r.y + f2m.y; e[2] = f1r.z + f2m.z; e[3] = f1r.w + f2m.w;
        float w[4];
#pragma unroll
        for (int h = 0; h < 4; h++) {
            e[h] = e[h] >= 0.f ? e[h] : 0.2f * e[h];
            if (m < 0) e[h] = -1e30f;
        }
#pragma unroll
        for (int h = 0; h < 4; h++) {
            float mx = e[h];
#pragma unroll
            for (int mm = 1; mm < 32; mm <<= 1) mx = fmaxf(mx, __shfl_xor(mx, mm));
            w[h] = expf(e[h] - mx);
            float sm = w[h];
#pragma unroll
            for (int mm = 1; mm < 32; mm <<= 1) sm += __shfl_xor(sm, mm);
            w[h] *= 0.25f / sm;
        }
        int w01 = (int)pack_f16(w[0], w[1]);
        int w23 = (int)pack_f16(w[2], w[3]);
        int moff = mc << 10;
        int dmax = deg0 > deg1 ? deg0 : deg1;
        int srcbase = lane & 32;
        const char* wbl = (const char*)WhTb + l32 * 32;   // this lane's 16 cols
        float a0 = 0.f, a1 = 0.f, a2 = 0.f, a3 = 0.f;

        int vo0, vo1, vo2;
        unsigned c01_0, c23_0, c01_1, c23_1, c01_2, c23_2;
        uint4 A0, B0, A1, B1, A2, B2;
#define LDST(K, VO, C01, C23, AA, BB)                                   \
        {                                                               \
            int k_ = (K);                                               \
            int val_ = (k_ < dmax) ? 1 : 0;                             \
            int s_ = srcbase + (val_ ? k_ : 0);                         \
            VO = __shfl(moff, s_);                                      \
            unsigned t01_ = (unsigned)__shfl(w01, s_);                  \
            unsigned t23_ = (unsigned)__shfl(w23, s_);                  \
            C01 = val_ ? t01_ : 0u;                                     \
            C23 = val_ ? t23_ : 0u;                                     \
            AA = *(const uint4*)(wbl + VO);                             \
            BB = *(const uint4*)(wbl + VO + 16);                        \
        }
#define CONS(C01, C23, AA, BB)                                          \
        {                                                               \
            f16x2 p01_ = BC16(C01), p23_ = BC16(C23);                   \
            FDOT2(BC16(AA.x), p01_, a0);                                \
            FDOT2(BC16(AA.y), p23_, a0);                                \
            FDOT2(BC16(AA.z), p01_, a1);                                \
            FDOT2(BC16(AA.w), p23_, a1);                                \
            FDOT2(BC16(BB.x), p01_, a2);                                \
            FDOT2(BC16(BB.y), p23_, a2);                                \
            FDOT2(BC16(BB.z), p01_, a3);                                \
            FDOT2(BC16(BB.w), p23_, a3);                                \
        }
        LDST(0, vo0, c01_0, c23_0, A0, B0);
        LDST(1, vo1, c01_1, c23_1, A1, B1);
        LDST(2, vo2, c01_2, c23_2, A2, B2);
        for (int j = 0; j < dmax; j += 3) {
            CONS(c01_0, c23_0, A0, B0);
            LDST(j + 3, vo0, c01_0, c23_0, A0, B0);
            CONS(c01_1, c23_1, A1, B1);
            LDST(j + 4, vo1, c01_1, c23_1, A1, B1);
            CONS(c01_2, c23_2, A2, B2);
            LDST(j + 5, vo2, c01_2, c23_2, A2, B2);
        }
#undef LDST
#undef CONS
        *(float4*)&G_a[((size_t)hop * BNc + row) * Dz + l32 * 4] = make_float4(a0, a1, a2, a3);
    } else {
        int row0 = (b << 10) | (r2 << 1);
        attn_row_full(WhTb, ffh, idx, deg0, b, row0, lane,
                      &G_a[((size_t)hop * BNc + row0) * Dz]);
        attn_row_full(WhTb, ffh, idx, deg1, b, row0 + 1, lane,
                      &G_a[((size_t)hop * BNc + row0 + 1) * Dz]);
    }
}

// ---------------- logits: one wave per row, 4 rows per block ------------------------------
__global__ __launch_bounds__(256) void k_logits4(const float* __restrict__ G_a, int hopA,
                                                 const float* __restrict__ u,
                                                 float* __restrict__ logits) {
    int row = blockIdx.x * 4 + (threadIdx.x >> 6);
    int lane = threadIdx.x & 63;
    int b = row >> 10;
    const float* g = G_a + ((size_t)hopA * BNc + row) * Dz;
    const float* ub = u + b * Dz;
    float s = g[lane] * ub[lane] + g[lane + 64] * ub[lane + 64];
#pragma unroll
    for (int off = 32; off; off >>= 1) s += __shfl_down(s, off);
    if (lane == 0) logits[row] = s;
}

// ---------------- u update: 8 blocks per batch, redundant softmax stats -------------------
__global__ __launch_bounds__(256) void k_upd(const float* __restrict__ G_a, int hopC,
                                             const float* __restrict__ logits,
                                             float* __restrict__ u) {
    int b = blockIdx.x >> 3;
    int chunk = blockIdx.x & 7;
    int t = threadIdx.x;                  // 256
    __shared__ float sp[1024];
    __shared__ float red[10];
    __shared__ float part[2][128];
    const float* l = logits + (size_t)b * Nz;
    float4 lv = *((const float4*)l + t);
    float mx = fmaxf(fmaxf(lv.x, lv.y), fmaxf(lv.z, lv.w));
#pragma unroll
    for (int mm = 1; mm < 64; mm <<= 1) mx = fmaxf(mx, __shfl_xor(mx, mm));
    if ((t & 63) == 0) red[t >> 6] = mx;
    __syncthreads();
    if (t == 0) {
        float m = red[0];
        for (int i = 1; i < 4; i++) m = fmaxf(m, red[i]);
        red[8] = m;
    }
    __syncthreads();
    mx = red[8];
    float e0 = expf(lv.x - mx), e1 = expf(lv.y - mx), e2 = expf(lv.z - mx), e3 = expf(lv.w - mx);
    float sum = e0 + e1 + e2 + e3;
#pragma unroll
    for (int mm = 1; mm < 64; mm <<= 1) sum += __shfl_xor(sum, mm);
    if ((t & 63) == 0) red[4 + (t >> 6)] = sum;
    __syncthreads();
    if (t == 0) {
        float ss = 0.f;
        for (int i = 0; i < 4; i++) ss += red[4 + i];
        red[9] = 1.f / ss;
    }
    __syncthreads();
    float inv = red[9];
    sp[t * 4] = e0 * inv;
    sp[t * 4 + 1] = e1 * inv;
    sp[t * 4 + 2] = e2 * inv;
    sp[t * 4 + 3] = e3 * inv;
    __syncthreads();
    int d = t & 127, half = t >> 7;
    const float* gc = G_a + ((size_t)hopC * BNc + (b << 10) + chunk * 128 + half * 64) * Dz + d;
    const float* pc = &sp[chunk * 128 + half * 64];
    float acc = 0.f;
#pragma unroll 4
    for (int j = 0; j < 64; j++) acc += gc[(size_t)j * Dz] * pc[j];
    part[half][d] = acc;
    __syncthreads();
    if (t < 128) atomicAdd(&u[b * Dz + t], part[0][t] + part[1][t]);
}

// ---------------- final out: sigmoid(logits), u, logits -----------------------------------
__global__ void k_fin(const float* __restrict__ logits, const float* __restrict__ u,
                      float* __restrict__ out) {
    int i = blockIdx.x * 256 + threadIdx.x;
    if (i < Bz * Nz) {
        float l = logits[i];
        out[i] = 1.f / (1.f + expf(-l));
        out[Bz * Nz + Bz * Dz + i] = l;
    }
    if (i < Bz * Dz) out[Bz * Nz + i] = u[i];
}

// ---------------- host ---------------------------------------------------------------------
extern "C" void kernel_launch(void* const* d_in, const int* in_sizes, int n_in,
                              void* d_out, int out_size, void* d_ws, size_t ws_size,
                              hipStream_t stream) {
    const int*   story    = (const int*)d_in[0];
    const int*   kb_len   = (const int*)d_in[1];
    const int*   conv_len = (const int*)d_in[2];
    const float* hidden   = (const float*)d_in[3];
    const float* dh       = (const float*)d_in[4];
    const float* adj      = (const float*)d_in[5];
    const float* emb      = (const float*)d_in[6];
    const float* gat_W    = (const float*)d_in[7];
    const float* gat_a    = (const float*)d_in[8];
    float* out = (float*)d_out;

    char* w = (char*)d_ws;
    auto alloc = [&](size_t bytes) {
        char* pp = w;
        w += (bytes + 255) & ~(size_t)255;
        return pp;
    };
    const size_t BN = (size_t)Bz * Nz;
    int*            idx  = (int*)           alloc(BN * CAP * 4);          // 8.4 MB
    int*            cnt  = (int*)           alloc(BN * 4);
    unsigned short* xhi  = (unsigned short*)alloc(4 * BN * Dz * 2);       // 16.8 MB
    unsigned short* wt   = (unsigned short*)alloc(4 * NC * 128 * 2);      // 0.6 MB
    unsigned short* WhT  = (unsigned short*)alloc(4 * BN * 512 * 2);      // 67 MB
    float*          ff   = (float*)         alloc(4 * BN * 8 * 4);        // 2.1 MB
    float*          G    = (float*)         alloc(4 * BN * Dz * 4);       // 33.6 MB
    float*          logits = (float*)       alloc(BN * 4);
    float*          u    = (float*)         alloc((size_t)Bz * Dz * 4);

    k_prep<<<BNc + 1152 + 8, 256, 0, stream>>>(adj, kb_len, conv_len, gat_W, gat_a, hidden,
                                               idx, cnt, wt, u);
    k_embed4<<<BNc, 128, 0, stream>>>(story, emb, dh, kb_len, conv_len, xhi);
    k_whf4<<<4608, 256, 0, stream>>>(xhi, wt, WhT, ff);
    k_attn4<<<8192, 256, 0, stream>>>(WhT, ff, idx, cnt, G);
    for (int hop = 0; hop < 3; hop++) {
        k_logits4<<<BNc / 4, 256, 0, stream>>>(G, hop, u, logits);
        k_upd<<<Bz * 8, 256, 0, stream>>>(G, hop + 1, logits, u);
    }
    k_fin<<<(Bz * Nz + 255) / 256, 256, 0, stream>>>(logits, u, out);
}